// Round 4
// baseline (1160.208 us; speedup 1.0000x reference)
//
#include <hip/hip_runtime.h>
#include <hip/hip_bf16.h>

#define NND 100000
#define NED 3200000
#define F 256
#define NCLS 64

typedef _Float16 f16x8 __attribute__((ext_vector_type(8)));
typedef _Float16 f16x4 __attribute__((ext_vector_type(4)));
typedef float f32x4 __attribute__((ext_vector_type(4)));

// ---------------- degree ----------------
__global__ __launch_bounds__(256) void k_deg(const int* __restrict__ dst, int* __restrict__ deg) {
    int i = blockIdx.x * 256 + threadIdx.x;
    if (i < NED) atomicAdd(&deg[dst[i]], 1);
}

// ---------------- CSR build: scan + fill ----------------
__global__ __launch_bounds__(256) void k_scan1(const int* __restrict__ deg, int* __restrict__ start, int* __restrict__ bsum) {
    __shared__ int sh[256];
    int i = blockIdx.x * 256 + threadIdx.x;
    int v = (i < NND) ? deg[i] : 0;
    sh[threadIdx.x] = v;
    __syncthreads();
    for (int off = 1; off < 256; off <<= 1) {
        int t = (threadIdx.x >= off) ? sh[threadIdx.x - off] : 0;
        __syncthreads();
        sh[threadIdx.x] += t;
        __syncthreads();
    }
    if (i < NND) start[i] = sh[threadIdx.x] - v;  // exclusive within block
    if (threadIdx.x == 255) bsum[blockIdx.x] = sh[255];
}

__global__ __launch_bounds__(512) void k_scan2(int* __restrict__ bsum, int nb) {
    __shared__ int sh[512];
    int tid = threadIdx.x;
    int v = (tid < nb) ? bsum[tid] : 0;
    sh[tid] = v;
    __syncthreads();
    for (int off = 1; off < 512; off <<= 1) {
        int t = (tid >= off) ? sh[tid - off] : 0;
        __syncthreads();
        sh[tid] += t;
        __syncthreads();
    }
    if (tid < nb) bsum[tid] = sh[tid] - v;  // exclusive
}

// scan3 + norm fused
__global__ __launch_bounds__(256) void k_scan3(int* __restrict__ start, const int* __restrict__ bsum,
                                               const int* __restrict__ deg, float* __restrict__ norm) {
    int i = blockIdx.x * 256 + threadIdx.x;
    if (i < NND) {
        start[i] += bsum[blockIdx.x];
        float d = (float)deg[i];
        norm[i] = rsqrtf(d < 1.0f ? 1.0f : d);
    }
}

__global__ __launch_bounds__(256) void k_fill(const int* __restrict__ src, const int* __restrict__ dst,
                                              const int* __restrict__ start, int* __restrict__ cursor,
                                              int* __restrict__ col) {
    int i = blockIdx.x * 256 + threadIdx.x;
    if (i < NED) {
        int d = dst[i];
        int p = start[d] + atomicAdd(&cursor[d], 1);
        col[p] = src[i];
    }
}

// ---------------- LayerNorm (one wave per node) -> pre-scaled fp16 (norm * LN) ----------------
__global__ __launch_bounds__(256) void k_ln(const float* __restrict__ x, const float* __restrict__ gamma,
                                            const float* __restrict__ beta, const float* __restrict__ norm,
                                            _Float16* __restrict__ y) {
    int node = blockIdx.x * 4 + (threadIdx.x >> 6);
    int lane = threadIdx.x & 63;
    if (node >= NND) return;
    float4 v = ((const float4*)x)[node * 64 + lane];
    float s = v.x + v.y + v.z + v.w;
    float s2 = v.x * v.x + v.y * v.y + v.z * v.z + v.w * v.w;
    for (int m = 1; m < 64; m <<= 1) {
        s += __shfl_xor(s, m, 64);
        s2 += __shfl_xor(s2, m, 64);
    }
    float mu = s * (1.0f / 256.0f);
    float var = s2 * (1.0f / 256.0f) - mu * mu;
    float rs = rsqrtf(var + 1e-5f);
    float w = norm[node];
    float4 g = ((const float4*)gamma)[lane];
    float4 b = ((const float4*)beta)[lane];
    f16x4 o;
    o[0] = (_Float16)(w * ((v.x - mu) * rs * g.x + b.x));
    o[1] = (_Float16)(w * ((v.y - mu) * rs * g.y + b.y));
    o[2] = (_Float16)(w * ((v.z - mu) * rs * g.z + b.z));
    o[3] = (_Float16)(w * ((v.w - mu) * rs * g.w + b.w));
    *(f16x4*)(y + (size_t)node * F + lane * 4) = o;
}

// ---------------- one propagation hop ----------------
// x is pre-scaled by norm. LAST=0: write norm^2 * sum. LAST=1: write norm * sum.
template <int LAST>
__global__ __launch_bounds__(256) void k_hop(const _Float16* __restrict__ x, _Float16* __restrict__ y,
                                             const int* __restrict__ start, const int* __restrict__ deg,
                                             const int* __restrict__ col, const float* __restrict__ norm) {
    int node = __builtin_amdgcn_readfirstlane(blockIdx.x * 4 + (threadIdx.x >> 6));
    if (node >= NND) return;
    int lane = threadIdx.x & 63;
    int hf = lane >> 5;       // which edge of the pair
    int l = lane & 31;        // 32 lanes x 8 halfs = 256 feats
    int s0 = start[node];
    int cnt = deg[node];
    float wd = norm[node];
    float acc[8] = {0.f, 0.f, 0.f, 0.f, 0.f, 0.f, 0.f, 0.f};
    const size_t loff = (size_t)l * 8;

    int nfull = cnt >> 6;     // full chunks of 64 edges
    for (int c = 0; c < nfull; c++) {
        int cv = col[s0 + c * 64 + lane];
#pragma unroll 8
        for (int i = 0; i < 32; i++) {
            int s = __shfl(cv, 2 * i + hf, 64);
            f16x8 v = *(const f16x8*)(x + (size_t)s * F + loff);
#pragma unroll
            for (int j = 0; j < 8; j++) acc[j] += (float)v[j];
        }
    }
    int rem = cnt & 63;
    if (rem) {
        int cv = (lane < rem) ? col[s0 + nfull * 64 + lane] : 0;
        int npair = rem >> 1;
#pragma unroll 4
        for (int i = 0; i < npair; i++) {
            int s = __shfl(cv, 2 * i + hf, 64);
            f16x8 v = *(const f16x8*)(x + (size_t)s * F + loff);
#pragma unroll
            for (int j = 0; j < 8; j++) acc[j] += (float)v[j];
        }
        if (rem & 1) {
            int s = __shfl(cv, rem - 1, 64);
            if (hf == 0) {
                f16x8 v = *(const f16x8*)(x + (size_t)s * F + loff);
#pragma unroll
                for (int j = 0; j < 8; j++) acc[j] += (float)v[j];
            }
        }
    }
#pragma unroll
    for (int j = 0; j < 8; j++) acc[j] += __shfl_xor(acc[j], 32, 64);
    if (hf == 0) {
        float sc = LAST ? wd : wd * wd;
        f16x8 o;
#pragma unroll
        for (int j = 0; j < 8; j++) o[j] = (_Float16)(acc[j] * sc);
        *(f16x8*)(y + (size_t)node * F + loff) = o;
    }
}

// ---------------- fp32 -> fp16 cast (weights) ----------------
__global__ __launch_bounds__(256) void k_cast(const float4* __restrict__ x, f16x4* __restrict__ y, int n4) {
    int i = blockIdx.x * 256 + threadIdx.x;
    if (i < n4) {
        float4 v = x[i];
        f16x4 o;
        o[0] = (_Float16)v.x; o[1] = (_Float16)v.y; o[2] = (_Float16)v.z; o[3] = (_Float16)v.w;
        y[i] = o;
    }
}

// ---------------- fused GEMM: relu(h3 @ Wc^T + bc) @ Wf^T + bf ----------------
__global__ __launch_bounds__(256) void k_gemm(const _Float16* __restrict__ A,
                                              const _Float16* __restrict__ Wc, const float* __restrict__ bc,
                                              const _Float16* __restrict__ Wf, const float* __restrict__ bf,
                                              float* __restrict__ out) {
    __shared__ _Float16 mid[16][264];   // +8 pad kills bank conflicts
    int wave = threadIdx.x >> 6, lane = threadIdx.x & 63;
    int l15 = lane & 15, lhi = lane >> 4;
    int row0 = blockIdx.x * 16;
    const _Float16* arow = A + (size_t)(row0 + l15) * F + lhi * 8;
    int ncol0 = wave * 64;
    f32x4 acc[4];
    for (int t = 0; t < 4; t++) acc[t] = (f32x4){0.f, 0.f, 0.f, 0.f};
#pragma unroll
    for (int kt = 0; kt < 8; kt++) {
        f16x8 a = *(const f16x8*)(arow + kt * 32);
#pragma unroll
        for (int t = 0; t < 4; t++) {
            int n = ncol0 + t * 16 + l15;
            f16x8 b = *(const f16x8*)(Wc + (size_t)n * F + lhi * 8 + kt * 32);
            acc[t] = __builtin_amdgcn_mfma_f32_16x16x32_f16(a, b, acc[t], 0, 0, 0);
        }
    }
#pragma unroll
    for (int t = 0; t < 4; t++) {
        int colb = ncol0 + t * 16 + l15;
        float bv = bc[colb];
#pragma unroll
        for (int r = 0; r < 4; r++) {
            float v = acc[t][r] + bv;
            mid[lhi * 4 + r][colb] = (_Float16)(v > 0.f ? v : 0.f);
        }
    }
    __syncthreads();
    // phase 2: each wave computes output cols [wave*16, wave*16+16)
    f32x4 acc2 = (f32x4){0.f, 0.f, 0.f, 0.f};
    int colb = wave * 16 + l15;
    const _Float16* brow = Wf + (size_t)colb * F + lhi * 8;
#pragma unroll
    for (int kt = 0; kt < 8; kt++) {
        f16x8 a = *(const f16x8*)&mid[l15][lhi * 8 + kt * 32];
        f16x8 b = *(const f16x8*)(brow + kt * 32);
        acc2 = __builtin_amdgcn_mfma_f32_16x16x32_f16(a, b, acc2, 0, 0, 0);
    }
    float bv = bf[colb];
#pragma unroll
    for (int r = 0; r < 4; r++) {
        int row = row0 + lhi * 4 + r;
        out[(size_t)row * NCLS + colb] = acc2[r] + bv;
    }
}

extern "C" void kernel_launch(void* const* d_in, const int* in_sizes, int n_in,
                              void* d_out, int out_size, void* d_ws, size_t ws_size,
                              hipStream_t stream) {
    const float* features = (const float*)d_in[0];
    const int* edge_src = (const int*)d_in[1];
    const int* edge_dst = (const int*)d_in[2];
    const float* ln_gamma = (const float*)d_in[3];
    const float* ln_beta = (const float*)d_in[4];
    const float* W_conv = (const float*)d_in[5];
    const float* b_conv = (const float*)d_in[6];
    const float* W_fc = (const float*)d_in[7];
    const float* b_fc = (const float*)d_in[8];
    float* out = (float*)d_out;

    char* w = (char*)d_ws;
    const size_t HB2 = (size_t)NND * F * 2;            // 51,200,000 (fp16 h)
    _Float16* hA = (_Float16*)(w + 0);
    _Float16* hB = (_Float16*)(w + HB2);
    int* col = (int*)(w + 2 * HB2);                    // 102,400,000
    int* deg = (int*)(w + 115200000);
    int* start = (int*)(w + 115600000);
    int* cursor = (int*)(w + 116000000);
    float* norm = (float*)(w + 116400000);
    int* bsum = (int*)(w + 116800000);
    _Float16* Wc16 = (_Float16*)(w + 116802048);
    _Float16* Wf16 = (_Float16*)(w + 116933120);

    hipMemsetAsync(deg, 0, NND * sizeof(int), stream);
    hipMemsetAsync(cursor, 0, NND * sizeof(int), stream);

    const int EB = (NED + 255) / 256;   // 12500
    const int NB = (NND + 255) / 256;   // 391

    k_deg<<<EB, 256, 0, stream>>>(edge_dst, deg);
    k_scan1<<<NB, 256, 0, stream>>>(deg, start, bsum);
    k_scan2<<<1, 512, 0, stream>>>(bsum, NB);
    k_scan3<<<NB, 256, 0, stream>>>(start, bsum, deg, norm);
    k_fill<<<EB, 256, 0, stream>>>(edge_src, edge_dst, start, cursor, col);

    k_ln<<<NND / 4, 256, 0, stream>>>(features, ln_gamma, ln_beta, norm, hA);

    k_hop<0><<<NND / 4, 256, 0, stream>>>(hA, hB, start, deg, col, norm);
    k_hop<0><<<NND / 4, 256, 0, stream>>>(hB, hA, start, deg, col, norm);
    k_hop<1><<<NND / 4, 256, 0, stream>>>(hA, hB, start, deg, col, norm);

    k_cast<<<(F * F / 4 + 255) / 256, 256, 0, stream>>>((const float4*)W_conv, (f16x4*)Wc16, F * F / 4);
    k_cast<<<(NCLS * F / 4 + 255) / 256, 256, 0, stream>>>((const float4*)W_fc, (f16x4*)Wf16, NCLS * F / 4);

    k_gemm<<<NND / 16, 256, 0, stream>>>(hB, Wc16, b_conv, Wf16, b_fc, out);
}